// Round 1
// baseline (700.896 us; speedup 1.0000x reference)
//
#include <hip/hip_runtime.h>

#define N_NODES 50000
#define DFEAT 128

// ---------------- CSR build ----------------

__global__ void k_count(const int* __restrict__ dst, int E, int* __restrict__ cnt) {
    int i = blockIdx.x * blockDim.x + threadIdx.x;
    if (i < E) atomicAdd(&cnt[dst[i]], 1);
}

__global__ __launch_bounds__(1024) void k_scan(const int* __restrict__ cnt, int N,
                                               int* __restrict__ rowptr, int* __restrict__ cursor) {
    __shared__ int sums[1024];
    int tid = threadIdx.x;
    int chunk = (N + 1023) / 1024;
    int start = tid * chunk;
    int end = min(start + chunk, N);
    int s = 0;
    for (int i = start; i < end; ++i) s += cnt[i];
    sums[tid] = s;
    __syncthreads();
    for (int off = 1; off < 1024; off <<= 1) {
        int v = (tid >= off) ? sums[tid - off] : 0;
        __syncthreads();
        sums[tid] += v;
        __syncthreads();
    }
    int base = (tid == 0) ? 0 : sums[tid - 1];
    for (int i = start; i < end; ++i) {
        rowptr[i] = base;
        cursor[i] = base;
        base += cnt[i];
    }
    if (tid == 1023) rowptr[N] = sums[1023];
}

__global__ void k_scatter(const int* __restrict__ src, const int* __restrict__ dst, int E,
                          int* __restrict__ cursor, int* __restrict__ csr) {
    int i = blockIdx.x * blockDim.x + threadIdx.x;
    if (i < E) {
        int d = dst[i];
        int p = atomicAdd(&cursor[d], 1);
        csr[p] = src[i];
    }
}

// ---------------- mean aggregation (d=128), one wave per node ----------------

__global__ __launch_bounds__(256) void k_aggregate(const float* __restrict__ X,
                                                   const int* __restrict__ rowptr,
                                                   const int* __restrict__ csr,
                                                   float* __restrict__ M, int N) {
    int wave = (int)((blockIdx.x * blockDim.x + threadIdx.x) >> 6);
    int lane = threadIdx.x & 63;
    if (wave >= N) return;
    int beg = rowptr[wave], end = rowptr[wave + 1];
    float a0 = 0.f, a1 = 0.f;
    for (int e = beg; e < end; ++e) {
        int s = csr[e];
        const float2 v = *(const float2*)(X + (size_t)s * DFEAT + lane * 2);
        a0 += v.x;
        a1 += v.y;
    }
    float inv = 1.0f / (float)max(end - beg, 1);
    *(float2*)(M + (size_t)wave * DFEAT + lane * 2) = make_float2(a0 * inv, a1 * inv);
}

// ---------------- fused  out = M@Wl + X@Wr + b ; LayerNorm ; ReLU ----------------
// 16 nodes per 256-thread block; j = tid&127 output column, half = tid>>7 covers 8 nodes.

__global__ __launch_bounds__(256) void k_linear_ln_relu(
    const float* __restrict__ M, const float* __restrict__ X,
    const float* __restrict__ Wl, const float* __restrict__ Wr,
    const float* __restrict__ bias, const float* __restrict__ g, const float* __restrict__ bb,
    float* __restrict__ H, int N) {
    __shared__ float sm[16 * 128];
    __shared__ float sx[16 * 128];
    __shared__ float st[16 * 132];  // padded row stride
    int tid = threadIdx.x;
    int nodeBase = blockIdx.x * 16;

    for (int idx = tid; idx < 16 * 128; idx += 256) {
        int node = nodeBase + (idx >> 7);
        float mv = 0.f, xv = 0.f;
        if (node < N) {
            mv = M[(size_t)node * 128 + (idx & 127)];
            xv = X[(size_t)node * 128 + (idx & 127)];
        }
        sm[idx] = mv;
        sx[idx] = xv;
    }
    __syncthreads();

    int j = tid & 127;
    int half = tid >> 7;
    float acc[8];
#pragma unroll
    for (int i = 0; i < 8; ++i) acc[i] = 0.f;

    for (int k = 0; k < 128; ++k) {
        float wl = Wl[k * 128 + j];
        float wr = Wr[k * 128 + j];
#pragma unroll
        for (int i = 0; i < 8; ++i) {
            int node = half * 8 + i;
            acc[i] = fmaf(sm[node * 128 + k], wl, acc[i]);
            acc[i] = fmaf(sx[node * 128 + k], wr, acc[i]);
        }
    }

    float bj = bias[j];
#pragma unroll
    for (int i = 0; i < 8; ++i) st[(half * 8 + i) * 132 + j] = acc[i] + bj;
    __syncthreads();

    // LayerNorm + ReLU: 4 waves, each handles 4 nodes
    int wave = tid >> 6, lane = tid & 63;
    for (int q = 0; q < 4; ++q) {
        int node = wave * 4 + q;
        float2 v = *(float2*)&st[node * 132 + 2 * lane];
        float s = v.x + v.y, ss = v.x * v.x + v.y * v.y;
#pragma unroll
        for (int o = 1; o < 64; o <<= 1) {
            s += __shfl_xor(s, o, 64);
            ss += __shfl_xor(ss, o, 64);
        }
        float mu = s * (1.0f / 128.0f);
        float var = ss * (1.0f / 128.0f) - mu * mu;
        float rsig = rsqrtf(var + 1e-5f);
        int gn = nodeBase + node;
        if (gn < N) {
            float y0 = (v.x - mu) * rsig * g[2 * lane] + bb[2 * lane];
            float y1 = (v.y - mu) * rsig * g[2 * lane + 1] + bb[2 * lane + 1];
            y0 = fmaxf(y0, 0.f);
            y1 = fmaxf(y1, 0.f);
            *(float2*)(H + (size_t)gn * 128 + 2 * lane) = make_float2(y0, y1);
        }
    }
}

// ---------------- layer 3: project first (t = H@W3l, r = H@W3r + b3), then aggregate 2-dim ----------------

__global__ __launch_bounds__(256) void k_proj(const float* __restrict__ H,
                                              const float* __restrict__ W3l,
                                              const float* __restrict__ W3r,
                                              const float* __restrict__ b3,
                                              float* __restrict__ t, float* __restrict__ r, int N) {
    int gw = (int)((blockIdx.x * blockDim.x + threadIdx.x) >> 6);
    int lane = threadIdx.x & 63;
    if (gw >= N) return;
    float2 h = *(const float2*)(H + (size_t)gw * 128 + 2 * lane);
    float4 wl = *(const float4*)(W3l + 4 * lane);  // W[2l][0],W[2l][1],W[2l+1][0],W[2l+1][1]
    float4 wr = *(const float4*)(W3r + 4 * lane);
    float t0 = h.x * wl.x + h.y * wl.z;
    float t1 = h.x * wl.y + h.y * wl.w;
    float r0 = h.x * wr.x + h.y * wr.z;
    float r1 = h.x * wr.y + h.y * wr.w;
#pragma unroll
    for (int o = 1; o < 64; o <<= 1) {
        t0 += __shfl_xor(t0, o, 64);
        t1 += __shfl_xor(t1, o, 64);
        r0 += __shfl_xor(r0, o, 64);
        r1 += __shfl_xor(r1, o, 64);
    }
    if (lane == 0) {
        t[gw * 2 + 0] = t0;
        t[gw * 2 + 1] = t1;
        r[gw * 2 + 0] = r0 + b3[0];
        r[gw * 2 + 1] = r1 + b3[1];
    }
}

__global__ __launch_bounds__(256) void k_final(const float* __restrict__ t, const float* __restrict__ r,
                                               const int* __restrict__ rowptr, const int* __restrict__ csr,
                                               float* __restrict__ out, int N) {
    int n = blockIdx.x * blockDim.x + threadIdx.x;
    if (n >= N) return;
    int beg = rowptr[n], end = rowptr[n + 1];
    float a0 = 0.f, a1 = 0.f;
    for (int e = beg; e < end; ++e) {
        int s = csr[e];
        a0 += t[s * 2];
        a1 += t[s * 2 + 1];
    }
    float inv = 1.0f / (float)max(end - beg, 1);
    out[n * 2 + 0] = a0 * inv + r[n * 2 + 0];
    out[n * 2 + 1] = a1 * inv + r[n * 2 + 1];
}

// ---------------- launch ----------------

extern "C" void kernel_launch(void* const* d_in, const int* in_sizes, int n_in,
                              void* d_out, int out_size, void* d_ws, size_t ws_size,
                              hipStream_t stream) {
    const float* x   = (const float*)d_in[0];
    const int* eidx  = (const int*)d_in[1];
    const float* W1l = (const float*)d_in[2];
    const float* W1r = (const float*)d_in[3];
    const float* b1  = (const float*)d_in[4];
    const float* g1  = (const float*)d_in[5];
    const float* bb1 = (const float*)d_in[6];
    const float* W2l = (const float*)d_in[7];
    const float* W2r = (const float*)d_in[8];
    const float* b2  = (const float*)d_in[9];
    const float* g2  = (const float*)d_in[10];
    const float* bb2 = (const float*)d_in[11];
    const float* W3l = (const float*)d_in[12];
    const float* W3r = (const float*)d_in[13];
    const float* b3  = (const float*)d_in[14];
    float* out = (float*)d_out;

    const int N = N_NODES;
    const int E = in_sizes[1] / 2;
    const int* src = eidx;
    const int* dst = eidx + E;

    char* ws = (char*)d_ws;
    size_t off = 0;
    auto alloc = [&](size_t bytes) -> char* {
        char* p = ws + off;
        off += (bytes + 255) & ~(size_t)255;
        return p;
    };
    int* cnt     = (int*)alloc((size_t)N * sizeof(int));
    int* rowptr  = (int*)alloc((size_t)(N + 1) * sizeof(int));
    int* cursor  = (int*)alloc((size_t)(N + 1) * sizeof(int));
    int* csr     = (int*)alloc((size_t)E * sizeof(int));
    float* M     = (float*)alloc((size_t)N * 128 * sizeof(float));
    float* H     = (float*)alloc((size_t)N * 128 * sizeof(float));
    float* tbuf  = (float*)alloc((size_t)N * 2 * sizeof(float));
    float* rbuf  = (float*)alloc((size_t)N * 2 * sizeof(float));

    hipMemsetAsync(cnt, 0, (size_t)N * sizeof(int), stream);
    k_count<<<(E + 255) / 256, 256, 0, stream>>>(dst, E, cnt);
    k_scan<<<1, 1024, 0, stream>>>(cnt, N, rowptr, cursor);
    k_scatter<<<(E + 255) / 256, 256, 0, stream>>>(src, dst, E, cursor, csr);

    // layer 1
    k_aggregate<<<(N + 3) / 4, 256, 0, stream>>>(x, rowptr, csr, M, N);
    k_linear_ln_relu<<<(N + 15) / 16, 256, 0, stream>>>(M, x, W1l, W1r, b1, g1, bb1, H, N);
    // layer 2
    k_aggregate<<<(N + 3) / 4, 256, 0, stream>>>(H, rowptr, csr, M, N);
    k_linear_ln_relu<<<(N + 15) / 16, 256, 0, stream>>>(M, H, W2l, W2r, b2, g2, bb2, H, N);
    // layer 3: project to 2 dims first, then aggregate tiny messages
    k_proj<<<(N + 3) / 4, 256, 0, stream>>>(H, W3l, W3r, b3, tbuf, rbuf, N);
    k_final<<<(N + 255) / 256, 256, 0, stream>>>(tbuf, rbuf, rowptr, csr, out, N);
}

// Round 2
// 459.757 us; speedup vs baseline: 1.5245x; 1.5245x over previous
//
#include <hip/hip_runtime.h>

#define N_NODES 50000

typedef unsigned int uint;
typedef unsigned short ushort;
typedef __attribute__((ext_vector_type(8))) short bf16x8;
typedef __attribute__((ext_vector_type(4))) float f32x4;

__device__ inline float bf2f(uint u) { u <<= 16; return __builtin_bit_cast(float, u); }
__device__ inline ushort f2bf(float f) {
    uint u = __builtin_bit_cast(uint, f);
    u = (u + 0x7fffu + ((u >> 16) & 1u)) >> 16;
    return (ushort)u;
}

// ---------------- CSR build ----------------

__global__ void k_count(const int* __restrict__ dst, int E, int* __restrict__ cnt) {
    int i = blockIdx.x * blockDim.x + threadIdx.x;
    if (i < E) atomicAdd(&cnt[dst[i]], 1);
}

__global__ __launch_bounds__(1024) void k_scan(const int* __restrict__ cnt, int N,
                                               int* __restrict__ rowptr, int* __restrict__ cursor) {
    __shared__ int sums[1024];
    int tid = threadIdx.x;
    int chunk = (N + 1023) / 1024;
    int start = tid * chunk;
    int end = min(start + chunk, N);
    int s = 0;
    for (int i = start; i < end; ++i) s += cnt[i];
    sums[tid] = s;
    __syncthreads();
    for (int off = 1; off < 1024; off <<= 1) {
        int v = (tid >= off) ? sums[tid - off] : 0;
        __syncthreads();
        sums[tid] += v;
        __syncthreads();
    }
    int base = (tid == 0) ? 0 : sums[tid - 1];
    for (int i = start; i < end; ++i) {
        rowptr[i] = base;
        cursor[i] = base;
        base += cnt[i];
    }
    if (tid == 1023) rowptr[N] = sums[1023];
}

__global__ void k_scatter(const int* __restrict__ src, const int* __restrict__ dst, int E,
                          int* __restrict__ cursor, int* __restrict__ csr) {
    int i = blockIdx.x * blockDim.x + threadIdx.x;
    if (i < E) {
        int d = dst[i];
        int p = atomicAdd(&cursor[d], 1);
        csr[p] = src[i];
    }
}

// ---------------- conversions / weight packing ----------------

__global__ void k_cvt(const float* __restrict__ x, ushort* __restrict__ xb, int n4) {
    int i = blockIdx.x * blockDim.x + threadIdx.x;
    if (i < n4) {
        float4 v = ((const float4*)x)[i];
        ushort4 o;
        o.x = f2bf(v.x); o.y = f2bf(v.y); o.z = f2bf(v.z); o.w = f2bf(v.w);
        ((ushort4*)xb)[i] = o;
    }
}

// pack [Wl;Wr] (256x128 row-major fp32) into B-fragment order:
// out[((k>>3)*128 + n)*8 + (k&7)] = bf16(Wcat[k][n]),  k = s*32 + q*8 + ki
__global__ void k_pack_w(const float* __restrict__ Wl, const float* __restrict__ Wr,
                         ushort* __restrict__ out) {
    int idx = blockIdx.x * blockDim.x + threadIdx.x;  // 0..32767
    int k = idx >> 7, n = idx & 127;
    float v = (k < 128) ? Wl[k * 128 + n] : Wr[(k - 128) * 128 + n];
    out[((k >> 3) << 10) + (n << 3) + (k & 7)] = f2bf(v);
}

// ---------------- mean aggregation (bf16, d=128), one wave per node ----------------

__global__ __launch_bounds__(256) void k_aggregate_bf(const ushort* __restrict__ X,
                                                      const int* __restrict__ rowptr,
                                                      const int* __restrict__ csr,
                                                      ushort* __restrict__ M, int N) {
    int wave = (int)((blockIdx.x * blockDim.x + threadIdx.x) >> 6);
    int lane = threadIdx.x & 63;
    if (wave >= N) return;
    int beg = rowptr[wave], end = rowptr[wave + 1];
    float a0 = 0.f, a1 = 0.f;
    int e = beg;
    for (; e + 1 < end; e += 2) {
        int s0 = csr[e], s1 = csr[e + 1];
        uint v0 = *(const uint*)(X + (size_t)s0 * 128 + lane * 2);
        uint v1 = *(const uint*)(X + (size_t)s1 * 128 + lane * 2);
        a0 += bf2f(v0 & 0xffffu) + bf2f(v1 & 0xffffu);
        a1 += bf2f(v0 >> 16) + bf2f(v1 >> 16);
    }
    if (e < end) {
        uint v = *(const uint*)(X + (size_t)csr[e] * 128 + lane * 2);
        a0 += bf2f(v & 0xffffu);
        a1 += bf2f(v >> 16);
    }
    float inv = 1.0f / (float)max(end - beg, 1);
    uint o = (uint)f2bf(a0 * inv) | ((uint)f2bf(a1 * inv) << 16);
    *(uint*)(M + (size_t)wave * 128 + lane * 2) = o;
}

// ---------------- fused GEMM (MFMA) + bias + LayerNorm + ReLU ----------------
// C[node][col] = sum_k [M|X][node][k] * Wcat[k][col],  K=256, ncols=128
// block = 256 threads = 4 waves; wave covers 16 rows x 128 cols (8 MFMA tiles 16x16x32).
__global__ __launch_bounds__(256) void k_gemm_ln_relu(
    const ushort* __restrict__ Mb, const ushort* __restrict__ Xb,
    const ushort* __restrict__ Wp, const float* __restrict__ bias,
    const float* __restrict__ g, const float* __restrict__ bb,
    ushort* __restrict__ H, int N) {
    int tid = threadIdx.x;
    int wave = tid >> 6, lane = tid & 63;
    int l15 = lane & 15, q = lane >> 4;
    int rowBase = blockIdx.x * 64 + wave * 16;
    int arow = rowBase + l15;
    if (arow >= N) arow = N - 1;

    f32x4 acc[8];
#pragma unroll
    for (int t = 0; t < 8; ++t) acc[t] = (f32x4){0.f, 0.f, 0.f, 0.f};

    const ushort* aM = Mb + (size_t)arow * 128 + q * 8;
    const ushort* aX = Xb + (size_t)arow * 128 + q * 8;
    const ushort* wq = Wp + (size_t)q * 1024 + l15 * 8;

#pragma unroll
    for (int s = 0; s < 8; ++s) {
        // A fragment: A[m=lane&15][k = s*32 + q*8 + ki]
        bf16x8 a = *(const bf16x8*)((s < 4) ? (aM + s * 32) : (aX + (s - 4) * 32));
        const ushort* wbase = wq + (size_t)s * 4096;  // (s*4+q)*1024
#pragma unroll
        for (int t = 0; t < 8; ++t) {
            bf16x8 b = *(const bf16x8*)(wbase + t * 128);  // (t*16)*8
            acc[t] = __builtin_amdgcn_mfma_f32_16x16x32_bf16(a, b, acc[t], 0, 0, 0);
        }
    }

    // epilogue: C row = q*4+r (within tile), col = t*16 + l15
    float gj[8], bbj[8], bj[8];
#pragma unroll
    for (int t = 0; t < 8; ++t) {
        int col = t * 16 + l15;
        gj[t] = g[col]; bbj[t] = bb[col]; bj[t] = bias[col];
    }
#pragma unroll
    for (int r = 0; r < 4; ++r) {
        float c[8];
        float s = 0.f, ss = 0.f;
#pragma unroll
        for (int t = 0; t < 8; ++t) {
            c[t] = acc[t][r] + bj[t];
            s += c[t];
            ss += c[t] * c[t];
        }
        // reduce across the 16 lanes of this quad (lane bits 0-3)
        s += __shfl_xor(s, 1); ss += __shfl_xor(ss, 1);
        s += __shfl_xor(s, 2); ss += __shfl_xor(ss, 2);
        s += __shfl_xor(s, 4); ss += __shfl_xor(ss, 4);
        s += __shfl_xor(s, 8); ss += __shfl_xor(ss, 8);
        float mu = s * (1.0f / 128.0f);
        float var = ss * (1.0f / 128.0f) - mu * mu;
        float rsig = rsqrtf(var + 1e-5f);
        int node = rowBase + q * 4 + r;
        if (node < N) {
            ushort* hp = H + (size_t)node * 128;
#pragma unroll
            for (int t = 0; t < 8; ++t) {
                float y = (c[t] - mu) * rsig * gj[t] + bbj[t];
                y = fmaxf(y, 0.f);
                hp[t * 16 + l15] = f2bf(y);
            }
        }
    }
}

// ---------------- layer 3: project first, then aggregate 2-dim ----------------

__global__ __launch_bounds__(256) void k_proj(const ushort* __restrict__ H,
                                              const float* __restrict__ W3l,
                                              const float* __restrict__ W3r,
                                              const float* __restrict__ b3,
                                              float* __restrict__ t, float* __restrict__ r, int N) {
    int gw = (int)((blockIdx.x * blockDim.x + threadIdx.x) >> 6);
    int lane = threadIdx.x & 63;
    if (gw >= N) return;
    uint hv = *(const uint*)(H + (size_t)gw * 128 + lane * 2);
    float h0 = bf2f(hv & 0xffffu), h1 = bf2f(hv >> 16);
    float4 wl = *(const float4*)(W3l + 4 * lane);
    float4 wr = *(const float4*)(W3r + 4 * lane);
    float t0 = h0 * wl.x + h1 * wl.z;
    float t1 = h0 * wl.y + h1 * wl.w;
    float r0 = h0 * wr.x + h1 * wr.z;
    float r1 = h0 * wr.y + h1 * wr.w;
#pragma unroll
    for (int o = 1; o < 64; o <<= 1) {
        t0 += __shfl_xor(t0, o, 64);
        t1 += __shfl_xor(t1, o, 64);
        r0 += __shfl_xor(r0, o, 64);
        r1 += __shfl_xor(r1, o, 64);
    }
    if (lane == 0) {
        t[gw * 2 + 0] = t0;
        t[gw * 2 + 1] = t1;
        r[gw * 2 + 0] = r0 + b3[0];
        r[gw * 2 + 1] = r1 + b3[1];
    }
}

__global__ __launch_bounds__(256) void k_final(const float* __restrict__ t, const float* __restrict__ r,
                                               const int* __restrict__ rowptr, const int* __restrict__ csr,
                                               float* __restrict__ out, int N) {
    int n = blockIdx.x * blockDim.x + threadIdx.x;
    if (n >= N) return;
    int beg = rowptr[n], end = rowptr[n + 1];
    float a0 = 0.f, a1 = 0.f;
    for (int e = beg; e < end; ++e) {
        int s = csr[e];
        a0 += t[s * 2];
        a1 += t[s * 2 + 1];
    }
    float inv = 1.0f / (float)max(end - beg, 1);
    out[n * 2 + 0] = a0 * inv + r[n * 2 + 0];
    out[n * 2 + 1] = a1 * inv + r[n * 2 + 1];
}

// ---------------- launch ----------------

extern "C" void kernel_launch(void* const* d_in, const int* in_sizes, int n_in,
                              void* d_out, int out_size, void* d_ws, size_t ws_size,
                              hipStream_t stream) {
    const float* x   = (const float*)d_in[0];
    const int* eidx  = (const int*)d_in[1];
    const float* W1l = (const float*)d_in[2];
    const float* W1r = (const float*)d_in[3];
    const float* b1  = (const float*)d_in[4];
    const float* g1  = (const float*)d_in[5];
    const float* bb1 = (const float*)d_in[6];
    const float* W2l = (const float*)d_in[7];
    const float* W2r = (const float*)d_in[8];
    const float* b2  = (const float*)d_in[9];
    const float* g2  = (const float*)d_in[10];
    const float* bb2 = (const float*)d_in[11];
    const float* W3l = (const float*)d_in[12];
    const float* W3r = (const float*)d_in[13];
    const float* b3  = (const float*)d_in[14];
    float* out = (float*)d_out;

    const int N = N_NODES;
    const int E = in_sizes[1] / 2;
    const int* src = eidx;
    const int* dst = eidx + E;

    char* ws = (char*)d_ws;
    size_t off = 0;
    auto alloc = [&](size_t bytes) -> char* {
        char* p = ws + off;
        off += (bytes + 255) & ~(size_t)255;
        return p;
    };
    int* cnt    = (int*)alloc((size_t)N * sizeof(int));
    int* rowptr = (int*)alloc((size_t)(N + 1) * sizeof(int));
    int* cursor = (int*)alloc((size_t)(N + 1) * sizeof(int));
    int* csr    = (int*)alloc((size_t)E * sizeof(int));
    ushort* Xb  = (ushort*)alloc((size_t)N * 128 * sizeof(ushort));
    ushort* Mb  = (ushort*)alloc((size_t)N * 128 * sizeof(ushort));
    ushort* Hb  = (ushort*)alloc((size_t)N * 128 * sizeof(ushort));
    ushort* Wp1 = (ushort*)alloc((size_t)256 * 128 * sizeof(ushort));
    ushort* Wp2 = (ushort*)alloc((size_t)256 * 128 * sizeof(ushort));
    float* tbuf = (float*)alloc((size_t)N * 2 * sizeof(float));
    float* rbuf = (float*)alloc((size_t)N * 2 * sizeof(float));

    hipMemsetAsync(cnt, 0, (size_t)N * sizeof(int), stream);
    k_count<<<(E + 255) / 256, 256, 0, stream>>>(dst, E, cnt);
    k_scan<<<1, 1024, 0, stream>>>(cnt, N, rowptr, cursor);
    k_scatter<<<(E + 255) / 256, 256, 0, stream>>>(src, dst, E, cursor, csr);

    k_cvt<<<(N * 128 / 4 + 255) / 256, 256, 0, stream>>>(x, Xb, N * 128 / 4);
    k_pack_w<<<128, 256, 0, stream>>>(W1l, W1r, Wp1);
    k_pack_w<<<128, 256, 0, stream>>>(W2l, W2r, Wp2);

    // layer 1
    k_aggregate_bf<<<(N + 3) / 4, 256, 0, stream>>>(Xb, rowptr, csr, Mb, N);
    k_gemm_ln_relu<<<(N + 63) / 64, 256, 0, stream>>>(Mb, Xb, Wp1, b1, g1, bb1, Hb, N);
    // layer 2
    k_aggregate_bf<<<(N + 3) / 4, 256, 0, stream>>>(Hb, rowptr, csr, Mb, N);
    k_gemm_ln_relu<<<(N + 63) / 64, 256, 0, stream>>>(Mb, Hb, Wp2, b2, g2, bb2, Hb, N);
    // layer 3
    k_proj<<<(N + 3) / 4, 256, 0, stream>>>(Hb, W3l, W3r, b3, tbuf, rbuf, N);
    k_final<<<(N + 255) / 256, 256, 0, stream>>>(tbuf, rbuf, rowptr, csr, out, N);
}

// Round 3
// 307.586 us; speedup vs baseline: 2.2787x; 1.4947x over previous
//
#include <hip/hip_runtime.h>

#define N_NODES 50000
#define SCAN_NB ((N_NODES + 255) / 256)  // 196

typedef unsigned int uint;
typedef unsigned short ushort;
typedef __attribute__((ext_vector_type(8))) short bf16x8;
typedef __attribute__((ext_vector_type(4))) float f32x4;

__device__ inline float bf2f(uint u) { u <<= 16; return __builtin_bit_cast(float, u); }
__device__ inline ushort f2bf(float f) {
    uint u = __builtin_bit_cast(uint, f);
    u = (u + 0x7fffu + ((u >> 16) & 1u)) >> 16;
    return (ushort)u;
}

// ---------------- CSR build ----------------

__global__ void k_count(const int* __restrict__ dst, int E, int* __restrict__ cnt) {
    int i = blockIdx.x * blockDim.x + threadIdx.x;
    if (i < E) atomicAdd(&cnt[dst[i]], 1);
}

__global__ __launch_bounds__(256) void k_block_sums(const int* __restrict__ cnt, int N,
                                                    int* __restrict__ bsum) {
    int i = blockIdx.x * 256 + threadIdx.x;
    int v = (i < N) ? cnt[i] : 0;
#pragma unroll
    for (int o = 1; o < 64; o <<= 1) v += __shfl_xor(v, o, 64);
    __shared__ int ws[4];
    if ((threadIdx.x & 63) == 0) ws[threadIdx.x >> 6] = v;
    __syncthreads();
    if (threadIdx.x == 0) bsum[blockIdx.x] = ws[0] + ws[1] + ws[2] + ws[3];
}

__global__ __launch_bounds__(256) void k_scan_bsums(int* __restrict__ bsum, int nb) {
    int t = threadIdx.x;
    int v = (t < nb) ? bsum[t] : 0;
    int lane = t & 63, w = t >> 6;
    int x = v;
#pragma unroll
    for (int o = 1; o < 64; o <<= 1) {
        int y = __shfl_up(x, o, 64);
        if (lane >= o) x += y;
    }
    __shared__ int ws[4];
    if (lane == 63) ws[w] = x;
    __syncthreads();
    int add = 0;
    for (int k = 0; k < 4; ++k)
        if (k < w) add += ws[k];
    if (t < nb) bsum[t] = x + add - v;  // exclusive prefix
}

__global__ __launch_bounds__(256) void k_write_rowptr(const int* __restrict__ cnt, int N,
                                                      const int* __restrict__ bpre,
                                                      int* __restrict__ rowptr,
                                                      int* __restrict__ cursor) {
    int b = blockIdx.x, t = threadIdx.x;
    int i = b * 256 + t;
    int v = (i < N) ? cnt[i] : 0;
    int lane = t & 63, w = t >> 6;
    int x = v;
#pragma unroll
    for (int o = 1; o < 64; o <<= 1) {
        int y = __shfl_up(x, o, 64);
        if (lane >= o) x += y;
    }
    __shared__ int ws[4];
    if (lane == 63) ws[w] = x;
    __syncthreads();
    int add = bpre[b];
    for (int k = 0; k < 4; ++k)
        if (k < w) add += ws[k];
    int excl = x - v + add;
    if (i < N) { rowptr[i] = excl; cursor[i] = excl; }
    if (i == N - 1) rowptr[N] = excl + v;
}

__global__ void k_scatter(const int* __restrict__ src, const int* __restrict__ dst, int E,
                          int* __restrict__ cursor, int* __restrict__ csr) {
    int i = blockIdx.x * blockDim.x + threadIdx.x;
    if (i < E) {
        int d = dst[i];
        int p = atomicAdd(&cursor[d], 1);
        csr[p] = src[i];
    }
}

// ---------------- conversions / weight packing ----------------

__global__ void k_cvt(const float* __restrict__ x, ushort* __restrict__ xb, int n4) {
    int i = blockIdx.x * blockDim.x + threadIdx.x;
    if (i < n4) {
        float4 v = ((const float4*)x)[i];
        ushort4 o;
        o.x = f2bf(v.x); o.y = f2bf(v.y); o.z = f2bf(v.z); o.w = f2bf(v.w);
        ((ushort4*)xb)[i] = o;
    }
}

// pack [Wl;Wr] (256x128 row-major fp32) into B-fragment order:
// out[((k>>3)*128 + n)*8 + (k&7)] = bf16(Wcat[k][n])
__global__ void k_pack_w(const float* __restrict__ Wl, const float* __restrict__ Wr,
                         ushort* __restrict__ out) {
    int idx = blockIdx.x * blockDim.x + threadIdx.x;  // 0..32767
    int k = idx >> 7, n = idx & 127;
    float v = (k < 128) ? Wl[k * 128 + n] : Wr[(k - 128) * 128 + n];
    out[((k >> 3) << 10) + (n << 3) + (k & 7)] = f2bf(v);
}

// ---------------- mean aggregation (bf16, d=128), one wave per node ----------------

__global__ __launch_bounds__(256) void k_aggregate_bf(const ushort* __restrict__ X,
                                                      const int* __restrict__ rowptr,
                                                      const int* __restrict__ csr,
                                                      ushort* __restrict__ M, int N) {
    int wv = (int)((blockIdx.x * blockDim.x + threadIdx.x) >> 6);
    int node = __builtin_amdgcn_readfirstlane(wv);
    int lane = threadIdx.x & 63;
    if (node >= N) return;
    int beg = rowptr[node], end = rowptr[node + 1];
    float a0 = 0.f, a1 = 0.f, b0 = 0.f, b1 = 0.f;
    int e = beg;
    for (; e + 3 < end; e += 4) {
        int s0 = csr[e], s1 = csr[e + 1], s2 = csr[e + 2], s3 = csr[e + 3];
        uint v0 = *(const uint*)(X + (size_t)s0 * 128 + lane * 2);
        uint v1 = *(const uint*)(X + (size_t)s1 * 128 + lane * 2);
        uint v2 = *(const uint*)(X + (size_t)s2 * 128 + lane * 2);
        uint v3 = *(const uint*)(X + (size_t)s3 * 128 + lane * 2);
        a0 += bf2f(v0 & 0xffffu) + bf2f(v1 & 0xffffu);
        a1 += bf2f(v0 >> 16) + bf2f(v1 >> 16);
        b0 += bf2f(v2 & 0xffffu) + bf2f(v3 & 0xffffu);
        b1 += bf2f(v2 >> 16) + bf2f(v3 >> 16);
    }
    for (; e < end; ++e) {
        uint v = *(const uint*)(X + (size_t)csr[e] * 128 + lane * 2);
        a0 += bf2f(v & 0xffffu);
        a1 += bf2f(v >> 16);
    }
    a0 += b0; a1 += b1;
    float inv = 1.0f / (float)max(end - beg, 1);
    uint o = (uint)f2bf(a0 * inv) | ((uint)f2bf(a1 * inv) << 16);
    *(uint*)(M + (size_t)node * 128 + lane * 2) = o;
}

// ---------------- fused GEMM (MFMA) + bias + LayerNorm + ReLU (+ optional layer-3 projection) ----
// C[node][col] = sum_k [M|X][node][k] * Wcat[k][col],  K=256, ncols=128
// block = 256 threads = 4 waves; wave covers 16 rows x 128 cols (8 MFMA tiles 16x16x32).
__global__ __launch_bounds__(256) void k_gemm_ln_relu(
    const ushort* __restrict__ Mb, const ushort* __restrict__ Xb,
    const ushort* __restrict__ Wp, const float* __restrict__ bias,
    const float* __restrict__ g, const float* __restrict__ bb,
    ushort* __restrict__ H, int N,
    const float* __restrict__ W3l, const float* __restrict__ W3r,
    const float* __restrict__ b3, float* __restrict__ tb, float* __restrict__ rb) {
    int tid = threadIdx.x;
    int wave = tid >> 6, lane = tid & 63;
    int l15 = lane & 15, q = lane >> 4;
    int rowBase = blockIdx.x * 64 + wave * 16;
    int arow = rowBase + l15;
    if (arow >= N) arow = N - 1;

    f32x4 acc[8];
#pragma unroll
    for (int t = 0; t < 8; ++t) acc[t] = (f32x4){0.f, 0.f, 0.f, 0.f};

    const ushort* aM = Mb + (size_t)arow * 128 + q * 8;
    const ushort* aX = Xb + (size_t)arow * 128 + q * 8;
    const ushort* wq = Wp + (size_t)q * 1024 + l15 * 8;

#pragma unroll
    for (int s = 0; s < 8; ++s) {
        bf16x8 a = *(const bf16x8*)((s < 4) ? (aM + s * 32) : (aX + (s - 4) * 32));
        const ushort* wbase = wq + (size_t)s * 4096;
#pragma unroll
        for (int t = 0; t < 8; ++t) {
            bf16x8 b = *(const bf16x8*)(wbase + t * 128);
            acc[t] = __builtin_amdgcn_mfma_f32_16x16x32_bf16(a, b, acc[t], 0, 0, 0);
        }
    }

    const bool doProj = (tb != nullptr);
    float gj[8], bbj[8], bj[8];
    float wl0[8], wl1[8], wr0[8], wr1[8];
#pragma unroll
    for (int t = 0; t < 8; ++t) {
        int col = t * 16 + l15;
        gj[t] = g[col]; bbj[t] = bb[col]; bj[t] = bias[col];
    }
    if (doProj) {
#pragma unroll
        for (int t = 0; t < 8; ++t) {
            int col = t * 16 + l15;
            float2 a = *(const float2*)(W3l + col * 2);
            float2 c2 = *(const float2*)(W3r + col * 2);
            wl0[t] = a.x; wl1[t] = a.y; wr0[t] = c2.x; wr1[t] = c2.y;
        }
    }

#pragma unroll
    for (int r = 0; r < 4; ++r) {
        float c[8];
        float s = 0.f, ss = 0.f;
#pragma unroll
        for (int t = 0; t < 8; ++t) {
            c[t] = acc[t][r] + bj[t];
            s += c[t];
            ss += c[t] * c[t];
        }
        s += __shfl_xor(s, 1); ss += __shfl_xor(ss, 1);
        s += __shfl_xor(s, 2); ss += __shfl_xor(ss, 2);
        s += __shfl_xor(s, 4); ss += __shfl_xor(ss, 4);
        s += __shfl_xor(s, 8); ss += __shfl_xor(ss, 8);
        float mu = s * (1.0f / 128.0f);
        float var = ss * (1.0f / 128.0f) - mu * mu;
        float rsig = rsqrtf(var + 1e-5f);
        int node = rowBase + q * 4 + r;
        float y[8];
#pragma unroll
        for (int t = 0; t < 8; ++t) {
            float v = (c[t] - mu) * rsig * gj[t] + bbj[t];
            y[t] = fmaxf(v, 0.f);
        }
        if (!doProj) {
            if (node < N) {
                ushort* hp = H + (size_t)node * 128;
#pragma unroll
                for (int t = 0; t < 8; ++t) hp[t * 16 + l15] = f2bf(y[t]);
            }
        } else {
            float t0 = 0.f, t1 = 0.f, r0 = 0.f, r1 = 0.f;
#pragma unroll
            for (int t = 0; t < 8; ++t) {
                t0 += y[t] * wl0[t];
                t1 += y[t] * wl1[t];
                r0 += y[t] * wr0[t];
                r1 += y[t] * wr1[t];
            }
#pragma unroll
            for (int o = 1; o < 16; o <<= 1) {
                t0 += __shfl_xor(t0, o);
                t1 += __shfl_xor(t1, o);
                r0 += __shfl_xor(r0, o);
                r1 += __shfl_xor(r1, o);
            }
            if (l15 == 0 && node < N) {
                tb[node * 2 + 0] = t0;
                tb[node * 2 + 1] = t1;
                rb[node * 2 + 0] = r0 + b3[0];
                rb[node * 2 + 1] = r1 + b3[1];
            }
        }
    }
}

// ---------------- layer 3 aggregate (2-dim) ----------------

__global__ __launch_bounds__(256) void k_final(const float* __restrict__ t, const float* __restrict__ r,
                                               const int* __restrict__ rowptr, const int* __restrict__ csr,
                                               float* __restrict__ out, int N) {
    int n = blockIdx.x * blockDim.x + threadIdx.x;
    if (n >= N) return;
    int beg = rowptr[n], end = rowptr[n + 1];
    float a0 = 0.f, a1 = 0.f;
    for (int e = beg; e < end; ++e) {
        int s = csr[e];
        a0 += t[s * 2];
        a1 += t[s * 2 + 1];
    }
    float inv = 1.0f / (float)max(end - beg, 1);
    out[n * 2 + 0] = a0 * inv + r[n * 2 + 0];
    out[n * 2 + 1] = a1 * inv + r[n * 2 + 1];
}

// ---------------- launch ----------------

extern "C" void kernel_launch(void* const* d_in, const int* in_sizes, int n_in,
                              void* d_out, int out_size, void* d_ws, size_t ws_size,
                              hipStream_t stream) {
    const float* x   = (const float*)d_in[0];
    const int* eidx  = (const int*)d_in[1];
    const float* W1l = (const float*)d_in[2];
    const float* W1r = (const float*)d_in[3];
    const float* b1  = (const float*)d_in[4];
    const float* g1  = (const float*)d_in[5];
    const float* bb1 = (const float*)d_in[6];
    const float* W2l = (const float*)d_in[7];
    const float* W2r = (const float*)d_in[8];
    const float* b2  = (const float*)d_in[9];
    const float* g2  = (const float*)d_in[10];
    const float* bb2 = (const float*)d_in[11];
    const float* W3l = (const float*)d_in[12];
    const float* W3r = (const float*)d_in[13];
    const float* b3  = (const float*)d_in[14];
    float* out = (float*)d_out;

    const int N = N_NODES;
    const int E = in_sizes[1] / 2;
    const int* src = eidx;
    const int* dst = eidx + E;

    char* ws = (char*)d_ws;
    size_t off = 0;
    auto alloc = [&](size_t bytes) -> char* {
        char* p = ws + off;
        off += (bytes + 255) & ~(size_t)255;
        return p;
    };
    int* cnt    = (int*)alloc((size_t)N * sizeof(int));
    int* rowptr = (int*)alloc((size_t)(N + 1) * sizeof(int));
    int* cursor = (int*)alloc((size_t)(N + 1) * sizeof(int));
    int* bsum   = (int*)alloc((size_t)SCAN_NB * sizeof(int));
    int* csr    = (int*)alloc((size_t)E * sizeof(int));
    ushort* Xb  = (ushort*)alloc((size_t)N * 128 * sizeof(ushort));
    ushort* Mb  = (ushort*)alloc((size_t)N * 128 * sizeof(ushort));
    ushort* Hb  = (ushort*)alloc((size_t)N * 128 * sizeof(ushort));
    ushort* Wp1 = (ushort*)alloc((size_t)256 * 128 * sizeof(ushort));
    ushort* Wp2 = (ushort*)alloc((size_t)256 * 128 * sizeof(ushort));
    float* tbuf = (float*)alloc((size_t)N * 2 * sizeof(float));
    float* rbuf = (float*)alloc((size_t)N * 2 * sizeof(float));

    hipMemsetAsync(cnt, 0, (size_t)N * sizeof(int), stream);
    k_count<<<(E + 255) / 256, 256, 0, stream>>>(dst, E, cnt);
    k_block_sums<<<SCAN_NB, 256, 0, stream>>>(cnt, N, bsum);
    k_scan_bsums<<<1, 256, 0, stream>>>(bsum, SCAN_NB);
    k_write_rowptr<<<SCAN_NB, 256, 0, stream>>>(cnt, N, bsum, rowptr, cursor);
    k_scatter<<<(E + 255) / 256, 256, 0, stream>>>(src, dst, E, cursor, csr);

    k_cvt<<<(N * 128 / 4 + 255) / 256, 256, 0, stream>>>(x, Xb, N * 128 / 4);
    k_pack_w<<<128, 256, 0, stream>>>(W1l, W1r, Wp1);
    k_pack_w<<<128, 256, 0, stream>>>(W2l, W2r, Wp2);

    // layer 1
    k_aggregate_bf<<<(N + 3) / 4, 256, 0, stream>>>(Xb, rowptr, csr, Mb, N);
    k_gemm_ln_relu<<<(N + 63) / 64, 256, 0, stream>>>(Mb, Xb, Wp1, b1, g1, bb1, Hb, N,
                                                      nullptr, nullptr, nullptr, nullptr, nullptr);
    // layer 2 (+ fused layer-3 projection)
    k_aggregate_bf<<<(N + 3) / 4, 256, 0, stream>>>(Hb, rowptr, csr, Mb, N);
    k_gemm_ln_relu<<<(N + 63) / 64, 256, 0, stream>>>(Mb, Hb, Wp2, b2, g2, bb2, Hb, N,
                                                      W3l, W3r, b3, tbuf, rbuf);
    // layer 3 aggregate
    k_final<<<(N + 255) / 256, 256, 0, stream>>>(tbuf, rbuf, rowptr, csr, out, N);
}

// Round 4
// 268.701 us; speedup vs baseline: 2.6085x; 1.1447x over previous
//
#include <hip/hip_runtime.h>

#define N_NODES 50000
#define SCAN_NB ((N_NODES + 255) / 256)  // 196

typedef unsigned int uint;
typedef unsigned short ushort;
typedef __attribute__((ext_vector_type(8))) short bf16x8;
typedef __attribute__((ext_vector_type(4))) float f32x4;

__device__ inline float bf2f(uint u) { u <<= 16; return __builtin_bit_cast(float, u); }
__device__ inline ushort f2bf(float f) {
    uint u = __builtin_bit_cast(uint, f);
    u = (u + 0x7fffu + ((u >> 16) & 1u)) >> 16;
    return (ushort)u;
}

// ---------------- CSR build ----------------

// single atomic pass: count AND per-edge rank
__global__ void k_count_rank(const int* __restrict__ dst, int E,
                             int* __restrict__ cnt, int* __restrict__ rank) {
    int i = blockIdx.x * blockDim.x + threadIdx.x;
    if (i < E) rank[i] = atomicAdd(&cnt[dst[i]], 1);
}

__global__ __launch_bounds__(256) void k_block_sums(const int* __restrict__ cnt, int N,
                                                    int* __restrict__ bsum) {
    int i = blockIdx.x * 256 + threadIdx.x;
    int v = (i < N) ? cnt[i] : 0;
#pragma unroll
    for (int o = 1; o < 64; o <<= 1) v += __shfl_xor(v, o, 64);
    __shared__ int ws[4];
    if ((threadIdx.x & 63) == 0) ws[threadIdx.x >> 6] = v;
    __syncthreads();
    if (threadIdx.x == 0) bsum[blockIdx.x] = ws[0] + ws[1] + ws[2] + ws[3];
}

__global__ __launch_bounds__(256) void k_scan_bsums(int* __restrict__ bsum, int nb) {
    int t = threadIdx.x;
    int v = (t < nb) ? bsum[t] : 0;
    int lane = t & 63, w = t >> 6;
    int x = v;
#pragma unroll
    for (int o = 1; o < 64; o <<= 1) {
        int y = __shfl_up(x, o, 64);
        if (lane >= o) x += y;
    }
    __shared__ int ws[4];
    if (lane == 63) ws[w] = x;
    __syncthreads();
    int add = 0;
    for (int k = 0; k < 4; ++k)
        if (k < w) add += ws[k];
    if (t < nb) bsum[t] = x + add - v;  // exclusive prefix
}

__global__ __launch_bounds__(256) void k_write_rowptr(const int* __restrict__ cnt, int N,
                                                      const int* __restrict__ bpre,
                                                      int* __restrict__ rowptr) {
    int b = blockIdx.x, t = threadIdx.x;
    int i = b * 256 + t;
    int v = (i < N) ? cnt[i] : 0;
    int lane = t & 63, w = t >> 6;
    int x = v;
#pragma unroll
    for (int o = 1; o < 64; o <<= 1) {
        int y = __shfl_up(x, o, 64);
        if (lane >= o) x += y;
    }
    __shared__ int ws[4];
    if (lane == 63) ws[w] = x;
    __syncthreads();
    int add = bpre[b];
    for (int k = 0; k < 4; ++k)
        if (k < w) add += ws[k];
    int excl = x - v + add;
    if (i < N) rowptr[i] = excl;
    if (i == N - 1) rowptr[N] = excl + v;
}

// atomic-free placement
__global__ void k_place(const int* __restrict__ src, const int* __restrict__ dst,
                        const int* __restrict__ rank, const int* __restrict__ rowptr,
                        int E, int* __restrict__ csr) {
    int i = blockIdx.x * blockDim.x + threadIdx.x;
    if (i < E) csr[rowptr[dst[i]] + rank[i]] = src[i];
}

// ---------------- conversions / weight packing ----------------

__global__ void k_cvt(const float* __restrict__ x, ushort* __restrict__ xb, int n4) {
    int i = blockIdx.x * blockDim.x + threadIdx.x;
    if (i < n4) {
        float4 v = ((const float4*)x)[i];
        ushort4 o;
        o.x = f2bf(v.x); o.y = f2bf(v.y); o.z = f2bf(v.z); o.w = f2bf(v.w);
        ((ushort4*)xb)[i] = o;
    }
}

// pack [Wl;Wr] (256x128 row-major fp32) into B-fragment order:
// out[((k>>3)*128 + n)*8 + (k&7)] = bf16(Wcat[k][n])
__global__ void k_pack_w(const float* __restrict__ Wl, const float* __restrict__ Wr,
                         ushort* __restrict__ out) {
    int idx = blockIdx.x * blockDim.x + threadIdx.x;  // 0..32767
    int k = idx >> 7, n = idx & 127;
    float v = (k < 128) ? Wl[k * 128 + n] : Wr[(k - 128) * 128 + n];
    out[((k >> 3) << 10) + (n << 3) + (k & 7)] = f2bf(v);
}

// ---------------- mean aggregation (bf16, d=128) ----------------
// 2 nodes per wave: 32 lanes per node, uint2 (4 bf16) per lane.

__global__ __launch_bounds__(256) void k_aggregate_bf(const ushort* __restrict__ X,
                                                      const int* __restrict__ rowptr,
                                                      const int* __restrict__ csr,
                                                      ushort* __restrict__ M, int N) {
    int node = (int)((blockIdx.x * blockDim.x + threadIdx.x) >> 5);
    int lane = threadIdx.x & 31;
    if (node >= N) return;
    int beg = rowptr[node], end = rowptr[node + 1];
    float a0 = 0.f, a1 = 0.f, a2 = 0.f, a3 = 0.f;
    float b0 = 0.f, b1 = 0.f, b2 = 0.f, b3 = 0.f;
    int e = beg;
    for (; e + 3 < end; e += 4) {
        int s0 = csr[e], s1 = csr[e + 1], s2 = csr[e + 2], s3 = csr[e + 3];
        uint2 v0 = *(const uint2*)(X + (size_t)s0 * 128 + lane * 4);
        uint2 v1 = *(const uint2*)(X + (size_t)s1 * 128 + lane * 4);
        uint2 v2 = *(const uint2*)(X + (size_t)s2 * 128 + lane * 4);
        uint2 v3 = *(const uint2*)(X + (size_t)s3 * 128 + lane * 4);
        a0 += bf2f(v0.x & 0xffffu) + bf2f(v1.x & 0xffffu);
        a1 += bf2f(v0.x >> 16) + bf2f(v1.x >> 16);
        a2 += bf2f(v0.y & 0xffffu) + bf2f(v1.y & 0xffffu);
        a3 += bf2f(v0.y >> 16) + bf2f(v1.y >> 16);
        b0 += bf2f(v2.x & 0xffffu) + bf2f(v3.x & 0xffffu);
        b1 += bf2f(v2.x >> 16) + bf2f(v3.x >> 16);
        b2 += bf2f(v2.y & 0xffffu) + bf2f(v3.y & 0xffffu);
        b3 += bf2f(v2.y >> 16) + bf2f(v3.y >> 16);
    }
    for (; e < end; ++e) {
        uint2 v = *(const uint2*)(X + (size_t)csr[e] * 128 + lane * 4);
        a0 += bf2f(v.x & 0xffffu);
        a1 += bf2f(v.x >> 16);
        a2 += bf2f(v.y & 0xffffu);
        a3 += bf2f(v.y >> 16);
    }
    a0 += b0; a1 += b1; a2 += b2; a3 += b3;
    float inv = 1.0f / (float)max(end - beg, 1);
    uint2 o;
    o.x = (uint)f2bf(a0 * inv) | ((uint)f2bf(a1 * inv) << 16);
    o.y = (uint)f2bf(a2 * inv) | ((uint)f2bf(a3 * inv) << 16);
    *(uint2*)(M + (size_t)node * 128 + lane * 4) = o;
}

// ---------------- fused GEMM (MFMA) + bias + LayerNorm + ReLU (+ optional layer-3 projection) ----
__global__ __launch_bounds__(256) void k_gemm_ln_relu(
    const ushort* __restrict__ Mb, const ushort* __restrict__ Xb,
    const ushort* __restrict__ Wp, const float* __restrict__ bias,
    const float* __restrict__ g, const float* __restrict__ bb,
    ushort* __restrict__ H, int N,
    const float* __restrict__ W3l, const float* __restrict__ W3r,
    const float* __restrict__ b3, float* __restrict__ tb, float* __restrict__ rb) {
    int tid = threadIdx.x;
    int wave = tid >> 6, lane = tid & 63;
    int l15 = lane & 15, q = lane >> 4;
    int rowBase = blockIdx.x * 64 + wave * 16;
    int arow = rowBase + l15;
    if (arow >= N) arow = N - 1;

    f32x4 acc[8];
#pragma unroll
    for (int t = 0; t < 8; ++t) acc[t] = (f32x4){0.f, 0.f, 0.f, 0.f};

    const ushort* aM = Mb + (size_t)arow * 128 + q * 8;
    const ushort* aX = Xb + (size_t)arow * 128 + q * 8;
    const ushort* wq = Wp + (size_t)q * 1024 + l15 * 8;

#pragma unroll
    for (int s = 0; s < 8; ++s) {
        bf16x8 a = *(const bf16x8*)((s < 4) ? (aM + s * 32) : (aX + (s - 4) * 32));
        const ushort* wbase = wq + (size_t)s * 4096;
#pragma unroll
        for (int t = 0; t < 8; ++t) {
            bf16x8 b = *(const bf16x8*)(wbase + t * 128);
            acc[t] = __builtin_amdgcn_mfma_f32_16x16x32_bf16(a, b, acc[t], 0, 0, 0);
        }
    }

    const bool doProj = (tb != nullptr);
    float gj[8], bbj[8], bj[8];
    float wl0[8], wl1[8], wr0[8], wr1[8];
#pragma unroll
    for (int t = 0; t < 8; ++t) {
        int col = t * 16 + l15;
        gj[t] = g[col]; bbj[t] = bb[col]; bj[t] = bias[col];
    }
    if (doProj) {
#pragma unroll
        for (int t = 0; t < 8; ++t) {
            int col = t * 16 + l15;
            float2 a = *(const float2*)(W3l + col * 2);
            float2 c2 = *(const float2*)(W3r + col * 2);
            wl0[t] = a.x; wl1[t] = a.y; wr0[t] = c2.x; wr1[t] = c2.y;
        }
    }

#pragma unroll
    for (int r = 0; r < 4; ++r) {
        float c[8];
        float s = 0.f, ss = 0.f;
#pragma unroll
        for (int t = 0; t < 8; ++t) {
            c[t] = acc[t][r] + bj[t];
            s += c[t];
            ss += c[t] * c[t];
        }
        s += __shfl_xor(s, 1); ss += __shfl_xor(ss, 1);
        s += __shfl_xor(s, 2); ss += __shfl_xor(ss, 2);
        s += __shfl_xor(s, 4); ss += __shfl_xor(ss, 4);
        s += __shfl_xor(s, 8); ss += __shfl_xor(ss, 8);
        float mu = s * (1.0f / 128.0f);
        float var = ss * (1.0f / 128.0f) - mu * mu;
        float rsig = rsqrtf(var + 1e-5f);
        int node = rowBase + q * 4 + r;
        float y[8];
#pragma unroll
        for (int t = 0; t < 8; ++t) {
            float v = (c[t] - mu) * rsig * gj[t] + bbj[t];
            y[t] = fmaxf(v, 0.f);
        }
        if (!doProj) {
            if (node < N) {
                ushort* hp = H + (size_t)node * 128;
#pragma unroll
                for (int t = 0; t < 8; ++t) hp[t * 16 + l15] = f2bf(y[t]);
            }
        } else {
            float t0 = 0.f, t1 = 0.f, r0 = 0.f, r1 = 0.f;
#pragma unroll
            for (int t = 0; t < 8; ++t) {
                t0 += y[t] * wl0[t];
                t1 += y[t] * wl1[t];
                r0 += y[t] * wr0[t];
                r1 += y[t] * wr1[t];
            }
#pragma unroll
            for (int o = 1; o < 16; o <<= 1) {
                t0 += __shfl_xor(t0, o);
                t1 += __shfl_xor(t1, o);
                r0 += __shfl_xor(r0, o);
                r1 += __shfl_xor(r1, o);
            }
            if (l15 == 0 && node < N) {
                tb[node * 2 + 0] = t0;
                tb[node * 2 + 1] = t1;
                rb[node * 2 + 0] = r0 + b3[0];
                rb[node * 2 + 1] = r1 + b3[1];
            }
        }
    }
}

// ---------------- layer 3 aggregate (2-dim) ----------------

__global__ __launch_bounds__(256) void k_final(const float* __restrict__ t, const float* __restrict__ r,
                                               const int* __restrict__ rowptr, const int* __restrict__ csr,
                                               float* __restrict__ out, int N) {
    int n = blockIdx.x * blockDim.x + threadIdx.x;
    if (n >= N) return;
    int beg = rowptr[n], end = rowptr[n + 1];
    float a0 = 0.f, a1 = 0.f, b0 = 0.f, b1 = 0.f;
    int e = beg;
    for (; e + 3 < end; e += 4) {
        float2 v0 = *(const float2*)(t + csr[e] * 2);
        float2 v1 = *(const float2*)(t + csr[e + 1] * 2);
        float2 v2 = *(const float2*)(t + csr[e + 2] * 2);
        float2 v3 = *(const float2*)(t + csr[e + 3] * 2);
        a0 += v0.x + v1.x; a1 += v0.y + v1.y;
        b0 += v2.x + v3.x; b1 += v2.y + v3.y;
    }
    for (; e < end; ++e) {
        float2 v = *(const float2*)(t + csr[e] * 2);
        a0 += v.x; a1 += v.y;
    }
    a0 += b0; a1 += b1;
    float inv = 1.0f / (float)max(end - beg, 1);
    out[n * 2 + 0] = a0 * inv + r[n * 2 + 0];
    out[n * 2 + 1] = a1 * inv + r[n * 2 + 1];
}

// ---------------- launch ----------------

extern "C" void kernel_launch(void* const* d_in, const int* in_sizes, int n_in,
                              void* d_out, int out_size, void* d_ws, size_t ws_size,
                              hipStream_t stream) {
    const float* x   = (const float*)d_in[0];
    const int* eidx  = (const int*)d_in[1];
    const float* W1l = (const float*)d_in[2];
    const float* W1r = (const float*)d_in[3];
    const float* b1  = (const float*)d_in[4];
    const float* g1  = (const float*)d_in[5];
    const float* bb1 = (const float*)d_in[6];
    const float* W2l = (const float*)d_in[7];
    const float* W2r = (const float*)d_in[8];
    const float* b2  = (const float*)d_in[9];
    const float* g2  = (const float*)d_in[10];
    const float* bb2 = (const float*)d_in[11];
    const float* W3l = (const float*)d_in[12];
    const float* W3r = (const float*)d_in[13];
    const float* b3  = (const float*)d_in[14];
    float* out = (float*)d_out;

    const int N = N_NODES;
    const int E = in_sizes[1] / 2;
    const int* src = eidx;
    const int* dst = eidx + E;

    char* ws = (char*)d_ws;
    size_t off = 0;
    auto alloc = [&](size_t bytes) -> char* {
        char* p = ws + off;
        off += (bytes + 255) & ~(size_t)255;
        return p;
    };
    int* cnt    = (int*)alloc((size_t)N * sizeof(int));
    int* rowptr = (int*)alloc((size_t)(N + 1) * sizeof(int));
    int* bsum   = (int*)alloc((size_t)SCAN_NB * sizeof(int));
    int* csr    = (int*)alloc((size_t)E * sizeof(int));
    ushort* Xb  = (ushort*)alloc((size_t)N * 128 * sizeof(ushort));
    ushort* Mb  = (ushort*)alloc((size_t)N * 128 * sizeof(ushort));
    ushort* Hb  = (ushort*)alloc((size_t)N * 128 * sizeof(ushort));
    ushort* Wp1 = (ushort*)alloc((size_t)256 * 128 * sizeof(ushort));
    ushort* Wp2 = (ushort*)alloc((size_t)256 * 128 * sizeof(ushort));
    float* tbuf = (float*)alloc((size_t)N * 2 * sizeof(float));
    float* rbuf = (float*)alloc((size_t)N * 2 * sizeof(float));
    int* rank   = (int*)Mb;  // alias: rank only live during CSR build, Mb written after

    hipMemsetAsync(cnt, 0, (size_t)N * sizeof(int), stream);
    k_count_rank<<<(E + 255) / 256, 256, 0, stream>>>(dst, E, cnt, rank);
    k_block_sums<<<SCAN_NB, 256, 0, stream>>>(cnt, N, bsum);
    k_scan_bsums<<<1, 256, 0, stream>>>(bsum, SCAN_NB);
    k_write_rowptr<<<SCAN_NB, 256, 0, stream>>>(cnt, N, bsum, rowptr);
    k_place<<<(E + 255) / 256, 256, 0, stream>>>(src, dst, rank, rowptr, E, csr);

    k_cvt<<<(N * 128 / 4 + 255) / 256, 256, 0, stream>>>(x, Xb, N * 128 / 4);
    k_pack_w<<<128, 256, 0, stream>>>(W1l, W1r, Wp1);
    k_pack_w<<<128, 256, 0, stream>>>(W2l, W2r, Wp2);

    // layer 1
    k_aggregate_bf<<<(N + 7) / 8, 256, 0, stream>>>(Xb, rowptr, csr, Mb, N);
    k_gemm_ln_relu<<<(N + 63) / 64, 256, 0, stream>>>(Mb, Xb, Wp1, b1, g1, bb1, Hb, N,
                                                      nullptr, nullptr, nullptr, nullptr, nullptr);
    // layer 2 (+ fused layer-3 projection)
    k_aggregate_bf<<<(N + 7) / 8, 256, 0, stream>>>(Hb, rowptr, csr, Mb, N);
    k_gemm_ln_relu<<<(N + 63) / 64, 256, 0, stream>>>(Mb, Hb, Wp2, b2, g2, bb2, Hb, N,
                                                      W3l, W3r, b3, tbuf, rbuf);
    // layer 3 aggregate
    k_final<<<(N + 255) / 256, 256, 0, stream>>>(tbuf, rbuf, rowptr, csr, out, N);
}